// Round 1
// baseline (1328.481 us; speedup 1.0000x reference)
//
#include <hip/hip_runtime.h>

#define TOKENS 8192
#define HID 2048
#define NEXP 8

typedef float f32x4 __attribute__((ext_vector_type(4)));
typedef short bf16x8 __attribute__((ext_vector_type(8)));

// ws layout (bytes)
#define WS_XBF 0ULL
#define WS_ACT 33554432ULL            // 16512 x 2048 bf16 (padded rows)
#define WS_ROWTOK 101187584ULL        // 16512 int
#define WS_ROWPROB 101253632ULL       // 16512 float
#define WS_EIDX 101319680ULL          // 8192 int2
#define WS_PROBS 101385216ULL         // 8192 float2
#define WS_META 101450752ULL          // [0..7]=counts [8..15]=fill [16..23]=offsets

__device__ __forceinline__ unsigned short f2bf(float f) {
    union { float f; unsigned int u; } a; a.f = f;
    unsigned int r = a.u + 0x7fffu + ((a.u >> 16) & 1u);
    return (unsigned short)(r >> 16);
}

__device__ __forceinline__ int swz4(int r) { return (r ^ (r >> 2)) & 3; }

// read one 16x16x32 A/B fragment (8 bf16) from a [128 rows][32 k] bf16 tile
// stored with 16B-block XOR swizzle: lds[r][cb] holds global block (cb ^ swz4(r)).
// frag layout: elems 0-3 = k 4*(l>>4)+0..3 ; elems 4-7 = +16.
__device__ __forceinline__ bf16x8 frag_read(const char* tile, int rbase, int l) {
    int r = rbase + (l & 15);
    int g = l >> 4;
    int cb = g >> 1;
    int o8 = (g & 1) << 3;
    int s = swz4(r);
    const char* row = tile + r * 64;
    union { bf16x8 v; unsigned long long q[2]; } u;
    u.q[0] = *(const unsigned long long*)(row + (((cb     ) ^ s) << 4) + o8);
    u.q[1] = *(const unsigned long long*)(row + (((cb | 2) ^ s) << 4) + o8);
    return u.v;
}

__device__ __forceinline__ void gload16(void* ldsdst, const void* gsrc) {
    __builtin_amdgcn_global_load_lds(
        (const __attribute__((address_space(1))) void*)gsrc,
        (__attribute__((address_space(3))) void*)ldsdst, 16, 0, 0);
}

// ---------------------------------------------------------------- router
__global__ __launch_bounds__(256) void router_kernel(
    const float* __restrict__ x, const float* __restrict__ Wr,
    unsigned short* __restrict__ xbf, int2* __restrict__ eidx,
    float2* __restrict__ probs, int* __restrict__ meta) {
    __shared__ float wrt[NEXP * HID];   // 64 KiB, [e][i]
    int tid = threadIdx.x;
    for (int f = tid; f < HID * NEXP; f += 256) {
        int i = f >> 3, e = f & 7;
        wrt[e * HID + i] = Wr[f];
    }
    __syncthreads();
    int w = tid >> 6, l = tid & 63;
    int tok = blockIdx.x * 4 + w;
    const float4* xr = (const float4*)(x + (size_t)tok * HID);
    float acc[NEXP];
#pragma unroll
    for (int e = 0; e < NEXP; ++e) acc[e] = 0.f;
    unsigned long long* xbr = (unsigned long long*)(xbf + (size_t)tok * HID);
#pragma unroll
    for (int it = 0; it < 8; ++it) {
        float4 v = xr[it * 64 + l];
        int c0 = (it * 64 + l) * 4;
#pragma unroll
        for (int e = 0; e < NEXP; ++e) {
            float4 wv = *(const float4*)&wrt[e * HID + c0];
            acc[e] += v.x * wv.x + v.y * wv.y + v.z * wv.z + v.w * wv.w;
        }
        unsigned long long pk = (unsigned long long)f2bf(v.x)
                              | ((unsigned long long)f2bf(v.y) << 16)
                              | ((unsigned long long)f2bf(v.z) << 32)
                              | ((unsigned long long)f2bf(v.w) << 48);
        xbr[it * 64 + l] = pk;
    }
#pragma unroll
    for (int e = 0; e < NEXP; ++e) {
#pragma unroll
        for (int d = 1; d < 64; d <<= 1) acc[e] += __shfl_xor(acc[e], d, 64);
    }
    if (l == 0) {
        int e0 = 0; float v0 = acc[0];
#pragma unroll
        for (int e = 1; e < NEXP; ++e) if (acc[e] > v0) { v0 = acc[e]; e0 = e; }
        int e1 = -1; float v1 = 0.f;
#pragma unroll
        for (int e = 0; e < NEXP; ++e)
            if (e != e0 && (e1 < 0 || acc[e] > v1)) { v1 = acc[e]; e1 = e; }
        float a = __expf(v1 - v0);            // v1 <= v0 -> a in (0,1]
        float inv = 1.f / (1.f + a);
        int2 ei; ei.x = e0; ei.y = e1;
        float2 pp; pp.x = inv; pp.y = a * inv;
        eidx[tok] = ei;
        probs[tok] = pp;
        atomicAdd(&meta[e0], 1);
        atomicAdd(&meta[e1], 1);
    }
}

// ---------------------------------------------------------------- scan
__global__ void scan_kernel(int* __restrict__ meta) {
    if (threadIdx.x == 0) {
        int s = 0;
#pragma unroll
        for (int e = 0; e < NEXP; ++e) { meta[16 + e] = s; s += meta[e]; }
    }
}

// ---------------------------------------------------------------- build expanded rows
__global__ __launch_bounds__(256) void build_kernel(
    const int2* __restrict__ eidx, const float2* __restrict__ probs,
    int* __restrict__ meta, int* __restrict__ row_token, float* __restrict__ row_prob) {
    int t = blockIdx.x * 256 + threadIdx.x;
    if (t >= TOKENS) return;
    int2 e = eidx[t];
    float2 p = probs[t];
    int s0 = meta[16 + e.x] + atomicAdd(&meta[8 + e.x], 1);
    row_token[s0] = t; row_prob[s0] = p.x;
    int s1 = meta[16 + e.y] + atomicAdd(&meta[8 + e.y], 1);
    row_token[s1] = t; row_prob[s1] = p.y;
}

// ---------------------------------------------------------------- GEMM1: act = swiglu(x@Wg, x@Wu)
__global__ __launch_bounds__(256, 2) void gemm1_kernel(
    const unsigned short* __restrict__ xbf,
    const float* __restrict__ Wg, const float* __restrict__ Wu,
    const int* __restrict__ row_token, const int* __restrict__ meta,
    unsigned short* __restrict__ act) {
    int e = blockIdx.z;
    int cnt = meta[e];
    int rt = blockIdx.y;
    if (rt * 128 >= cnt) return;
    int off = meta[16 + e];
    int ct = blockIdx.x;
    __shared__ char lds[24576];
    char* At = lds;
    char* Bgt = lds + 8192;
    char* But = lds + 16384;
    int tid = threadIdx.x, w = tid >> 6, l = tid & 63;

    // A staging: gather token rows, pre-swizzled source, linear LDS dest
    const unsigned short* asrc[2];
    char* adst[2];
#pragma unroll
    for (int p = 0; p < 2; ++p) {
        int rl = w * 32 + p * 16 + (l >> 2);
        int r = rt * 128 + rl;
        if (r >= cnt) r = cnt - 1;
        int tok = row_token[off + r];
        asrc[p] = xbf + (size_t)tok * HID + (((l & 3) ^ swz4(rl)) << 3);
        adst[p] = At + w * 2048 + p * 1024;
    }
    // B staging: fp32 -> bf16 reg-staged transpose into [n][k] swizzled tile
    int n = ((w & 1) << 6) + l;
    int sn = swz4(n);
    const float* bsg[4];
    const float* bsu[4];
    int bdst[4];
    const float* wgb = Wg + (size_t)e * HID * HID + ct * 128 + n;
    const float* wub = Wu + (size_t)e * HID * HID + ct * 128 + n;
#pragma unroll
    for (int j = 0; j < 4; ++j) {
        int kg = j * 2 + (w >> 1);
        bsg[j] = wgb + (size_t)kg * 4 * HID;
        bsu[j] = wub + (size_t)kg * 4 * HID;
        bdst[j] = n * 64 + (((kg >> 1) ^ sn) << 4) + ((kg & 1) << 3);
    }
    int wr = w >> 1, wc = w & 1;

    f32x4 accg[4][4], accu[4][4];
    f32x4 z = {0.f, 0.f, 0.f, 0.f};
#pragma unroll
    for (int m = 0; m < 4; ++m)
#pragma unroll
        for (int nn = 0; nn < 4; ++nn) { accg[m][nn] = z; accu[m][nn] = z; }

    for (int kt = 0; kt < 64; ++kt) {
        gload16(adst[0], asrc[0] + (size_t)kt * 32);
        gload16(adst[1], asrc[1] + (size_t)kt * 32);
#pragma unroll
        for (int j = 0; j < 4; ++j) {
            const float* pg = bsg[j] + (size_t)kt * 32 * HID;
            const float* pu = bsu[j] + (size_t)kt * 32 * HID;
            unsigned long long pkg = (unsigned long long)f2bf(pg[0])
                                   | ((unsigned long long)f2bf(pg[HID]) << 16)
                                   | ((unsigned long long)f2bf(pg[2 * HID]) << 32)
                                   | ((unsigned long long)f2bf(pg[3 * HID]) << 48);
            unsigned long long pku = (unsigned long long)f2bf(pu[0])
                                   | ((unsigned long long)f2bf(pu[HID]) << 16)
                                   | ((unsigned long long)f2bf(pu[2 * HID]) << 32)
                                   | ((unsigned long long)f2bf(pu[3 * HID]) << 48);
            *(unsigned long long*)(Bgt + bdst[j]) = pkg;
            *(unsigned long long*)(But + bdst[j]) = pku;
        }
        __syncthreads();
        bf16x8 af[4];
#pragma unroll
        for (int m = 0; m < 4; ++m) af[m] = frag_read(At, wr * 64 + m * 16, l);
#pragma unroll
        for (int nn = 0; nn < 4; ++nn) {
            bf16x8 bfr = frag_read(Bgt, wc * 64 + nn * 16, l);
#pragma unroll
            for (int m = 0; m < 4; ++m)
                accg[m][nn] = __builtin_amdgcn_mfma_f32_16x16x32_bf16(af[m], bfr, accg[m][nn], 0, 0, 0);
        }
#pragma unroll
        for (int nn = 0; nn < 4; ++nn) {
            bf16x8 bfr = frag_read(But, wc * 64 + nn * 16, l);
#pragma unroll
            for (int m = 0; m < 4; ++m)
                accu[m][nn] = __builtin_amdgcn_mfma_f32_16x16x32_bf16(af[m], bfr, accu[m][nn], 0, 0, 0);
        }
        __syncthreads();
    }
    // epilogue: swiglu fuse, bf16 store
    int colbase = ct * 128 + wc * 64;
#pragma unroll
    for (int m = 0; m < 4; ++m) {
#pragma unroll
        for (int q = 0; q < 4; ++q) {
            int rloc = wr * 64 + m * 16 + (l >> 4) * 4 + q;
            int r = rt * 128 + rloc;
            if (r < cnt) {
                size_t rowoff = (size_t)(off + r) * HID;
#pragma unroll
                for (int nn = 0; nn < 4; ++nn) {
                    float g = accg[m][nn][q];
                    float u = accu[m][nn][q];
                    float sgl = g / (1.f + __expf(-g));
                    sgl = fminf(fmaxf(sgl, -7.f), 7.f);
                    act[rowoff + colbase + nn * 16 + (l & 15)] = f2bf(sgl * u);
                }
            }
        }
    }
}

// ---------------------------------------------------------------- GEMM2: out += p * (act @ Wd)
__global__ __launch_bounds__(256, 2) void gemm2_kernel(
    const unsigned short* __restrict__ act, const float* __restrict__ Wd,
    const int* __restrict__ row_token, const float* __restrict__ row_prob,
    const int* __restrict__ meta, float* __restrict__ out) {
    int e = blockIdx.z;
    int cnt = meta[e];
    int rt = blockIdx.y;
    if (rt * 128 >= cnt) return;
    int off = meta[16 + e];
    int ct = blockIdx.x;
    __shared__ char lds[16384];
    char* At = lds;
    char* Bt = lds + 8192;
    int tid = threadIdx.x, w = tid >> 6, l = tid & 63;

    const unsigned short* asrc[2];
    char* adst[2];
#pragma unroll
    for (int p = 0; p < 2; ++p) {
        int rl = w * 32 + p * 16 + (l >> 2);
        asrc[p] = act + (size_t)(off + rt * 128 + rl) * HID + (((l & 3) ^ swz4(rl)) << 3);
        adst[p] = At + w * 2048 + p * 1024;
    }
    int n = ((w & 1) << 6) + l;
    int sn = swz4(n);
    const float* bs[4];
    int bdst[4];
    const float* wdb = Wd + (size_t)e * HID * HID + ct * 128 + n;
#pragma unroll
    for (int j = 0; j < 4; ++j) {
        int kg = j * 2 + (w >> 1);
        bs[j] = wdb + (size_t)kg * 4 * HID;
        bdst[j] = n * 64 + (((kg >> 1) ^ sn) << 4) + ((kg & 1) << 3);
    }
    int wr = w >> 1, wc = w & 1;

    f32x4 acc[4][4];
    f32x4 z = {0.f, 0.f, 0.f, 0.f};
#pragma unroll
    for (int m = 0; m < 4; ++m)
#pragma unroll
        for (int nn = 0; nn < 4; ++nn) acc[m][nn] = z;

    for (int kt = 0; kt < 64; ++kt) {
        gload16(adst[0], asrc[0] + (size_t)kt * 32);
        gload16(adst[1], asrc[1] + (size_t)kt * 32);
#pragma unroll
        for (int j = 0; j < 4; ++j) {
            const float* p_ = bs[j] + (size_t)kt * 32 * HID;
            unsigned long long pk = (unsigned long long)f2bf(p_[0])
                                  | ((unsigned long long)f2bf(p_[HID]) << 16)
                                  | ((unsigned long long)f2bf(p_[2 * HID]) << 32)
                                  | ((unsigned long long)f2bf(p_[3 * HID]) << 48);
            *(unsigned long long*)(Bt + bdst[j]) = pk;
        }
        __syncthreads();
        bf16x8 af[4];
#pragma unroll
        for (int m = 0; m < 4; ++m) af[m] = frag_read(At, wr * 64 + m * 16, l);
#pragma unroll
        for (int nn = 0; nn < 4; ++nn) {
            bf16x8 bfr = frag_read(Bt, wc * 64 + nn * 16, l);
#pragma unroll
            for (int m = 0; m < 4; ++m)
                acc[m][nn] = __builtin_amdgcn_mfma_f32_16x16x32_bf16(af[m], bfr, acc[m][nn], 0, 0, 0);
        }
        __syncthreads();
    }
    int colbase = ct * 128 + wc * 64;
#pragma unroll
    for (int m = 0; m < 4; ++m) {
#pragma unroll
        for (int q = 0; q < 4; ++q) {
            int rloc = wr * 64 + m * 16 + (l >> 4) * 4 + q;
            int r = rt * 128 + rloc;
            if (r < cnt) {
                int slot = off + r;
                int tok = row_token[slot];
                float pr = row_prob[slot];
                float* orow = out + (size_t)tok * HID + colbase;
#pragma unroll
                for (int nn = 0; nn < 4; ++nn)
                    unsafeAtomicAdd(&orow[nn * 16 + (l & 15)], acc[m][nn][q] * pr);
            }
        }
    }
}

// ---------------------------------------------------------------- launch
extern "C" void kernel_launch(void* const* d_in, const int* in_sizes, int n_in,
                              void* d_out, int out_size, void* d_ws, size_t ws_size,
                              hipStream_t stream) {
    const float* x  = (const float*)d_in[0];
    const float* Wr = (const float*)d_in[1];
    const float* Wg = (const float*)d_in[2];
    const float* Wu = (const float*)d_in[3];
    const float* Wd = (const float*)d_in[4];
    float* out = (float*)d_out;
    char* ws = (char*)d_ws;

    unsigned short* xbf = (unsigned short*)(ws + WS_XBF);
    unsigned short* act = (unsigned short*)(ws + WS_ACT);
    int* row_token = (int*)(ws + WS_ROWTOK);
    float* row_prob = (float*)(ws + WS_ROWPROB);
    int2* eidx = (int2*)(ws + WS_EIDX);
    float2* probs = (float2*)(ws + WS_PROBS);
    int* meta = (int*)(ws + WS_META);

    hipMemsetAsync(d_out, 0, (size_t)out_size * sizeof(float), stream);
    hipMemsetAsync(meta, 0, 64, stream);   // counts + fill

    hipLaunchKernelGGL(router_kernel, dim3(TOKENS / 4), dim3(256), 0, stream,
                       x, Wr, xbf, eidx, probs, meta);
    hipLaunchKernelGGL(scan_kernel, dim3(1), dim3(64), 0, stream, meta);
    hipLaunchKernelGGL(build_kernel, dim3(TOKENS / 256), dim3(256), 0, stream,
                       eidx, probs, meta, row_token, row_prob);
    hipLaunchKernelGGL(gemm1_kernel, dim3(16, 64, NEXP), dim3(256), 0, stream,
                       xbf, Wg, Wu, row_token, meta, act);
    hipLaunchKernelGGL(gemm2_kernel, dim3(16, 64, NEXP), dim3(256), 0, stream,
                       act, Wd, row_token, row_prob, meta, out);
}

// Round 2
// 1015.529 us; speedup vs baseline: 1.3082x; 1.3082x over previous
//
#include <hip/hip_runtime.h>

#define TOKENS 8192
#define HID 2048
#define NEXP 8

typedef float f32x4 __attribute__((ext_vector_type(4)));
typedef short bf16x8 __attribute__((ext_vector_type(8)));

// ws layout (bytes)
#define WS_XBF     0ULL           // 8192 x 2048 bf16 (interleaved k)
#define WS_ACT     33554432ULL    // 16512 x 2048 bf16 (interleaved k)
#define WS_WGT     101187584ULL   // 8 x 2048 x 2048 bf16 [e][n][k-int]
#define WS_WUT     168296448ULL
#define WS_WDT     235405312ULL
#define WS_ROWTOK  302514176ULL   // 16512 int
#define WS_ROWPROB 302580224ULL   // 16512 float
#define WS_EIDX    302646272ULL   // 8192 int2
#define WS_PROBS   302711808ULL   // 8192 float2
#define WS_META    302777344ULL   // [0..7]=counts [8..15]=fill [16..23]=offsets

__device__ __forceinline__ unsigned short f2bf(float f) {
    union { float f; unsigned int u; } a; a.f = f;
    unsigned int r = a.u + 0x7fffu + ((a.u >> 16) & 1u);
    return (unsigned short)(r >> 16);
}

__device__ __forceinline__ int swz4(int r) { return (r ^ (r >> 2)) & 3; }

// Interleaved row layout: within each 32-k group (64 B), 16B unit g holds
// k = {4g..4g+3, 4g+16..4g+19} -- exactly one MFMA fragment for lane group g.
// Tile rows are 64 B; physical unit u at row r holds global unit u ^ swz4(r).
__device__ __forceinline__ bf16x8 frag128(const char* tile, int rbase, int l) {
    int r = rbase + (l & 15);
    int g = l >> 4;
    return *(const bf16x8*)(tile + r * 64 + (((g ^ swz4(r)) & 3) << 4));
}

__device__ __forceinline__ void gload16(void* ldsdst, const void* gsrc) {
    __builtin_amdgcn_global_load_lds(
        (const __attribute__((address_space(1))) void*)gsrc,
        (__attribute__((address_space(3))) void*)ldsdst, 16, 0, 0);
}

// ---------------------------------------------------------------- router
__global__ __launch_bounds__(256) void router_kernel(
    const float* __restrict__ x, const float* __restrict__ Wr,
    unsigned short* __restrict__ xbf, int2* __restrict__ eidx,
    float2* __restrict__ probs, int* __restrict__ meta) {
    __shared__ float wrt[NEXP * HID];   // 64 KiB, [e][i]
    int tid = threadIdx.x;
    for (int f = tid; f < HID * NEXP; f += 256) {
        int i = f >> 3, e = f & 7;
        wrt[e * HID + i] = Wr[f];
    }
    __syncthreads();
    int w = tid >> 6, l = tid & 63;
    int tok = blockIdx.x * 4 + w;
    const float4* xr = (const float4*)(x + (size_t)tok * HID);
    float acc[NEXP];
#pragma unroll
    for (int e = 0; e < NEXP; ++e) acc[e] = 0.f;
    unsigned long long* xbr = (unsigned long long*)(xbf + (size_t)tok * HID);
#pragma unroll
    for (int it = 0; it < 8; ++it) {
        float4 v = xr[it * 64 + l];
        int k0 = (it * 64 + l) * 4;
#pragma unroll
        for (int e = 0; e < NEXP; ++e) {
            float4 wv = *(const float4*)&wrt[e * HID + k0];
            acc[e] += v.x * wv.x + v.y * wv.y + v.z * wv.z + v.w * wv.w;
        }
        unsigned long long pk = (unsigned long long)f2bf(v.x)
                              | ((unsigned long long)f2bf(v.y) << 16)
                              | ((unsigned long long)f2bf(v.z) << 32)
                              | ((unsigned long long)f2bf(v.w) << 48);
        // interleaved qword index
        int qi = ((k0 >> 5) << 3) + (((k0 >> 2) & 3) << 1) + ((k0 >> 4) & 1);
        xbr[qi] = pk;
    }
#pragma unroll
    for (int e = 0; e < NEXP; ++e) {
#pragma unroll
        for (int d = 1; d < 64; d <<= 1) acc[e] += __shfl_xor(acc[e], d, 64);
    }
    if (l == 0) {
        int e0 = 0; float v0 = acc[0];
#pragma unroll
        for (int e = 1; e < NEXP; ++e) if (acc[e] > v0) { v0 = acc[e]; e0 = e; }
        int e1 = -1; float v1 = 0.f;
#pragma unroll
        for (int e = 0; e < NEXP; ++e)
            if (e != e0 && (e1 < 0 || acc[e] > v1)) { v1 = acc[e]; e1 = e; }
        float a = __expf(v1 - v0);
        float inv = 1.f / (1.f + a);
        int2 ei; ei.x = e0; ei.y = e1;
        float2 pp; pp.x = inv; pp.y = a * inv;
        eidx[tok] = ei;
        probs[tok] = pp;
        atomicAdd(&meta[e0], 1);
        atomicAdd(&meta[e1], 1);
    }
}

// ---------------------------------------------------------------- weight convert+transpose
// W[e][k][n] f32 -> O[e][n][k-interleaved] bf16 ; 64k x 64n tile per block
__global__ __launch_bounds__(256) void convert_kernel(
    const float* __restrict__ Wg, const float* __restrict__ Wu,
    const float* __restrict__ Wd, unsigned short* __restrict__ wt) {
    int mz = blockIdx.z;
    int mat = mz >> 3, e = mz & 7;
    const float* W = (mat == 0 ? Wg : (mat == 1 ? Wu : Wd)) + (size_t)e * HID * HID;
    unsigned short* O = wt + (size_t)mat * NEXP * HID * HID + (size_t)e * HID * HID;
    int kb = blockIdx.y * 64, nb = blockIdx.x * 64;
    __shared__ unsigned short t[64][68];   // [n][k], pitch 68 keeps b64 reads aligned
    int tid = threadIdx.x;
    int kr = tid >> 4;
    int nc = (tid & 15) * 4;
#pragma unroll
    for (int ki = 0; ki < 4; ++ki) {
        int k = kr + ki * 16;
        float4 v = *(const float4*)&W[(size_t)(kb + k) * HID + nb + nc];
        t[nc + 0][k] = f2bf(v.x);
        t[nc + 1][k] = f2bf(v.y);
        t[nc + 2][k] = f2bf(v.z);
        t[nc + 3][k] = f2bf(v.w);
    }
    __syncthreads();
    int q = tid & 15;
    int k0 = ((q >> 3) << 5) + (((q >> 1) & 3) << 2) + ((q & 1) << 4);  // local k of 4 consecutive
#pragma unroll
    for (int ni = 0; ni < 4; ++ni) {
        int n = (tid >> 4) + ni * 16;
        unsigned long long pk = (unsigned long long)t[n][k0]
                              | ((unsigned long long)t[n][k0 + 1] << 16)
                              | ((unsigned long long)t[n][k0 + 2] << 32)
                              | ((unsigned long long)t[n][k0 + 3] << 48);
        *(unsigned long long*)&O[(size_t)(nb + n) * HID + kb + q * 4] = pk;
    }
}

// ---------------------------------------------------------------- scan
__global__ void scan_kernel(int* __restrict__ meta) {
    if (threadIdx.x == 0) {
        int s = 0;
#pragma unroll
        for (int e = 0; e < NEXP; ++e) { meta[16 + e] = s; s += meta[e]; }
    }
}

// ---------------------------------------------------------------- build expanded rows
__global__ __launch_bounds__(256) void build_kernel(
    const int2* __restrict__ eidx, const float2* __restrict__ probs,
    int* __restrict__ meta, int* __restrict__ row_token, float* __restrict__ row_prob) {
    int t = blockIdx.x * 256 + threadIdx.x;
    if (t >= TOKENS) return;
    int2 e = eidx[t];
    float2 p = probs[t];
    int s0 = meta[16 + e.x] + atomicAdd(&meta[8 + e.x], 1);
    row_token[s0] = t; row_prob[s0] = p.x;
    int s1 = meta[16 + e.y] + atomicAdd(&meta[8 + e.y], 1);
    row_token[s1] = t; row_prob[s1] = p.y;
}

// ---------------------------------------------------------------- GEMM1: act = swiglu(x@Wg, x@Wu)
__global__ __launch_bounds__(256, 2) void gemm1_kernel(
    const unsigned short* __restrict__ xbf,
    const unsigned short* __restrict__ wgt, const unsigned short* __restrict__ wut,
    const int* __restrict__ row_token, const int* __restrict__ meta,
    unsigned short* __restrict__ act) {
    int e = blockIdx.z;
    int cnt = meta[e];
    int rt = blockIdx.y;
    if (rt * 128 >= cnt) return;
    int off = meta[16 + e];
    int ct = blockIdx.x;
    __shared__ __align__(16) char lds[24576];
    char* At = lds;
    char* Bg = lds + 8192;
    char* Bu = lds + 16384;
    int tid = threadIdx.x, w = tid >> 6, l = tid & 63;
    int wr = w >> 1, wc = w & 1;

    const unsigned short *as[2], *bgs[2], *bus[2];
    int dof[2];
#pragma unroll
    for (int p = 0; p < 2; ++p) {
        int rl = w * 32 + p * 16 + (l >> 2);
        int su = ((l & 3) ^ swz4(rl)) << 3;   // pre-swizzled 16B unit (element offset)
        int r = rt * 128 + rl; if (r >= cnt) r = cnt - 1;
        int tok = row_token[off + r];
        as[p]  = xbf + (size_t)tok * HID + su;
        bgs[p] = wgt + (size_t)(e * HID + ct * 128 + rl) * HID + su;
        bus[p] = wut + (size_t)(e * HID + ct * 128 + rl) * HID + su;
        dof[p] = w * 2048 + p * 1024;
    }

    f32x4 accg[4][4], accu[4][4];
    f32x4 z = {0.f, 0.f, 0.f, 0.f};
#pragma unroll
    for (int m = 0; m < 4; ++m)
#pragma unroll
        for (int nn = 0; nn < 4; ++nn) { accg[m][nn] = z; accu[m][nn] = z; }

    for (int kt = 0; kt < 64; ++kt) {
        int ko = kt * 32;
        gload16(At + dof[0], as[0] + ko);
        gload16(At + dof[1], as[1] + ko);
        gload16(Bg + dof[0], bgs[0] + ko);
        gload16(Bg + dof[1], bgs[1] + ko);
        gload16(Bu + dof[0], bus[0] + ko);
        gload16(Bu + dof[1], bus[1] + ko);
        __syncthreads();
        bf16x8 af[4];
#pragma unroll
        for (int m = 0; m < 4; ++m) af[m] = frag128(At, wr * 64 + m * 16, l);
#pragma unroll
        for (int nn = 0; nn < 4; ++nn) {
            bf16x8 b = frag128(Bg, wc * 64 + nn * 16, l);
#pragma unroll
            for (int m = 0; m < 4; ++m)
                accg[m][nn] = __builtin_amdgcn_mfma_f32_16x16x32_bf16(af[m], b, accg[m][nn], 0, 0, 0);
        }
#pragma unroll
        for (int nn = 0; nn < 4; ++nn) {
            bf16x8 b = frag128(Bu, wc * 64 + nn * 16, l);
#pragma unroll
            for (int m = 0; m < 4; ++m)
                accu[m][nn] = __builtin_amdgcn_mfma_f32_16x16x32_bf16(af[m], b, accu[m][nn], 0, 0, 0);
        }
        __syncthreads();
    }
    // epilogue: swiglu, store act in interleaved-k layout (act is gemm2's A/k-dim)
    int cbase = ct * 128 + wc * 64;
    int r16 = l & 15;
    int csub = (r16 >> 2) * 8 + (r16 & 3);
#pragma unroll
    for (int m = 0; m < 4; ++m) {
#pragma unroll
        for (int q = 0; q < 4; ++q) {
            int rloc = wr * 64 + m * 16 + (l >> 4) * 4 + q;
            int r = rt * 128 + rloc;
            if (r < cnt) {
                unsigned short* arow = act + (size_t)(off + r) * HID;
#pragma unroll
                for (int nn = 0; nn < 4; ++nn) {
                    float g = accg[m][nn][q];
                    float u = accu[m][nn][q];
                    float sgl = g / (1.f + __expf(-g));
                    sgl = fminf(fmaxf(sgl, -7.f), 7.f);
                    arow[cbase + ((nn >> 1) << 5) + ((nn & 1) << 2) + csub] = f2bf(sgl * u);
                }
            }
        }
    }
}

// ---------------------------------------------------------------- GEMM2: out += p * (act @ Wd)
__global__ __launch_bounds__(256, 2) void gemm2_kernel(
    const unsigned short* __restrict__ act, const unsigned short* __restrict__ wdt,
    const int* __restrict__ row_token, const float* __restrict__ row_prob,
    const int* __restrict__ meta, float* __restrict__ out) {
    int e = blockIdx.z;
    int cnt = meta[e];
    int rt = blockIdx.y;
    if (rt * 128 >= cnt) return;
    int off = meta[16 + e];
    int ct = blockIdx.x;
    __shared__ __align__(16) char lds[16384];
    char* At = lds;
    char* Bt = lds + 8192;
    int tid = threadIdx.x, w = tid >> 6, l = tid & 63;
    int wr = w >> 1, wc = w & 1;

    const unsigned short *as[2], *bs[2];
    int dof[2];
#pragma unroll
    for (int p = 0; p < 2; ++p) {
        int rl = w * 32 + p * 16 + (l >> 2);
        int su = ((l & 3) ^ swz4(rl)) << 3;
        as[p] = act + (size_t)(off + rt * 128 + rl) * HID + su;   // padded buffer, no clamp
        bs[p] = wdt + (size_t)(e * HID + ct * 128 + rl) * HID + su;
        dof[p] = w * 2048 + p * 1024;
    }

    f32x4 acc[4][4];
    f32x4 z = {0.f, 0.f, 0.f, 0.f};
#pragma unroll
    for (int m = 0; m < 4; ++m)
#pragma unroll
        for (int nn = 0; nn < 4; ++nn) acc[m][nn] = z;

    for (int kt = 0; kt < 64; ++kt) {
        int ko = kt * 32;
        gload16(At + dof[0], as[0] + ko);
        gload16(At + dof[1], as[1] + ko);
        gload16(Bt + dof[0], bs[0] + ko);
        gload16(Bt + dof[1], bs[1] + ko);
        __syncthreads();
        bf16x8 af[4];
#pragma unroll
        for (int m = 0; m < 4; ++m) af[m] = frag128(At, wr * 64 + m * 16, l);
#pragma unroll
        for (int nn = 0; nn < 4; ++nn) {
            bf16x8 b = frag128(Bt, wc * 64 + nn * 16, l);
#pragma unroll
            for (int m = 0; m < 4; ++m)
                acc[m][nn] = __builtin_amdgcn_mfma_f32_16x16x32_bf16(af[m], b, acc[m][nn], 0, 0, 0);
        }
        __syncthreads();
    }
    int colbase = ct * 128 + wc * 64;
#pragma unroll
    for (int m = 0; m < 4; ++m) {
#pragma unroll
        for (int q = 0; q < 4; ++q) {
            int rloc = wr * 64 + m * 16 + (l >> 4) * 4 + q;
            int r = rt * 128 + rloc;
            if (r < cnt) {
                int slot = off + r;
                int tok = row_token[slot];
                float pr = row_prob[slot];
                float* orow = out + (size_t)tok * HID + colbase;
#pragma unroll
                for (int nn = 0; nn < 4; ++nn)
                    unsafeAtomicAdd(&orow[nn * 16 + (l & 15)], acc[m][nn][q] * pr);
            }
        }
    }
}

// ---------------------------------------------------------------- launch
extern "C" void kernel_launch(void* const* d_in, const int* in_sizes, int n_in,
                              void* d_out, int out_size, void* d_ws, size_t ws_size,
                              hipStream_t stream) {
    const float* x  = (const float*)d_in[0];
    const float* Wr = (const float*)d_in[1];
    const float* Wg = (const float*)d_in[2];
    const float* Wu = (const float*)d_in[3];
    const float* Wd = (const float*)d_in[4];
    float* out = (float*)d_out;
    char* ws = (char*)d_ws;

    unsigned short* xbf = (unsigned short*)(ws + WS_XBF);
    unsigned short* act = (unsigned short*)(ws + WS_ACT);
    unsigned short* wgt = (unsigned short*)(ws + WS_WGT);
    unsigned short* wut = (unsigned short*)(ws + WS_WUT);
    unsigned short* wdt = (unsigned short*)(ws + WS_WDT);
    int* row_token = (int*)(ws + WS_ROWTOK);
    float* row_prob = (float*)(ws + WS_ROWPROB);
    int2* eidx = (int2*)(ws + WS_EIDX);
    float2* probs = (float2*)(ws + WS_PROBS);
    int* meta = (int*)(ws + WS_META);

    hipMemsetAsync(d_out, 0, (size_t)out_size * sizeof(float), stream);
    hipMemsetAsync(meta, 0, 64, stream);

    hipLaunchKernelGGL(convert_kernel, dim3(32, 32, 24), dim3(256), 0, stream,
                       Wg, Wu, Wd, wgt);   // wgt/wut/wdt are contiguous in ws
    hipLaunchKernelGGL(router_kernel, dim3(TOKENS / 4), dim3(256), 0, stream,
                       x, Wr, xbf, eidx, probs, meta);
    hipLaunchKernelGGL(scan_kernel, dim3(1), dim3(64), 0, stream, meta);
    hipLaunchKernelGGL(build_kernel, dim3(TOKENS / 256), dim3(256), 0, stream,
                       eidx, probs, meta, row_token, row_prob);
    hipLaunchKernelGGL(gemm1_kernel, dim3(16, 64, NEXP), dim3(256), 0, stream,
                       xbf, wgt, wut, row_token, meta, act);
    hipLaunchKernelGGL(gemm2_kernel, dim3(16, 64, NEXP), dim3(256), 0, stream,
                       act, wdt, row_token, row_prob, meta, out);
}

// Round 3
// 938.898 us; speedup vs baseline: 1.4149x; 1.0816x over previous
//
#include <hip/hip_runtime.h>

#define TOKENS 8192
#define HID 2048
#define NEXP 8
#define NT 32          // K tiles = 2048/64

typedef float f32x4 __attribute__((ext_vector_type(4)));
typedef short bf16x8 __attribute__((ext_vector_type(8)));

// ws layout (bytes)
#define WS_XBF     0ULL           // 8192 x 2048 bf16 (interleaved k)
#define WS_ACT     33554432ULL    // 16384 x 2048 bf16 (interleaved k)
#define WS_WCAT    100663296ULL   // 8 x 4096 x 2048 bf16  [e][n'][k-int], n' = g/u 16-col interleave
#define WS_WDT     234881024ULL   // 8 x 2048 x 2048 bf16  [e][n][k-int]
#define WS_ROWTOK  301989888ULL   // 16384 int
#define WS_ROWPROB 302055424ULL   // 16384 float
#define WS_EIDX    302120960ULL   // 8192 int2
#define WS_PROBS   302186496ULL   // 8192 float2
#define WS_META    302252032ULL   // [0..7]=counts [8..15]=fill [16..23]=offsets

__device__ __forceinline__ unsigned short f2bf(float f) {
    union { float f; unsigned int u; } a; a.f = f;
    unsigned int r = a.u + 0x7fffu + ((a.u >> 16) & 1u);
    return (unsigned short)(r >> 16);
}

__device__ __forceinline__ void gload16(void* ldsdst, const void* gsrc) {
    __builtin_amdgcn_global_load_lds(
        (const __attribute__((address_space(1))) void*)gsrc,
        (__attribute__((address_space(3))) void*)ldsdst, 16, 0, 0);
}

#define BAR asm volatile("s_barrier" ::: "memory")
#define VM4 asm volatile("s_waitcnt vmcnt(4)" ::: "memory")
#define VM0 asm volatile("s_waitcnt vmcnt(0)" ::: "memory")

// ---------------------------------------------------------------- router
__global__ __launch_bounds__(256) void router_kernel(
    const float* __restrict__ x, const float* __restrict__ Wr,
    unsigned short* __restrict__ xbf, int2* __restrict__ eidx,
    float2* __restrict__ probs, int* __restrict__ meta) {
    __shared__ float wrt[NEXP * HID];   // 64 KiB, [e][i]
    int tid = threadIdx.x;
    for (int f = tid; f < HID * NEXP; f += 256) {
        int i = f >> 3, e = f & 7;
        wrt[e * HID + i] = Wr[f];
    }
    __syncthreads();
    int w = tid >> 6, l = tid & 63;
    int tok = blockIdx.x * 4 + w;
    const float4* xr = (const float4*)(x + (size_t)tok * HID);
    float acc[NEXP];
#pragma unroll
    for (int e = 0; e < NEXP; ++e) acc[e] = 0.f;
    unsigned long long* xbr = (unsigned long long*)(xbf + (size_t)tok * HID);
#pragma unroll
    for (int it = 0; it < 8; ++it) {
        float4 v = xr[it * 64 + l];
        int k0 = (it * 64 + l) * 4;
#pragma unroll
        for (int e = 0; e < NEXP; ++e) {
            float4 wv = *(const float4*)&wrt[e * HID + k0];
            acc[e] += v.x * wv.x + v.y * wv.y + v.z * wv.z + v.w * wv.w;
        }
        unsigned long long pk = (unsigned long long)f2bf(v.x)
                              | ((unsigned long long)f2bf(v.y) << 16)
                              | ((unsigned long long)f2bf(v.z) << 32)
                              | ((unsigned long long)f2bf(v.w) << 48);
        int qi = ((k0 >> 5) << 3) + (((k0 >> 2) & 3) << 1) + ((k0 >> 4) & 1);
        xbr[qi] = pk;
    }
#pragma unroll
    for (int e = 0; e < NEXP; ++e) {
#pragma unroll
        for (int d = 1; d < 64; d <<= 1) acc[e] += __shfl_xor(acc[e], d, 64);
    }
    if (l == 0) {
        int e0 = 0; float v0 = acc[0];
#pragma unroll
        for (int e = 1; e < NEXP; ++e) if (acc[e] > v0) { v0 = acc[e]; e0 = e; }
        int e1 = -1; float v1 = 0.f;
#pragma unroll
        for (int e = 0; e < NEXP; ++e)
            if (e != e0 && (e1 < 0 || acc[e] > v1)) { v1 = acc[e]; e1 = e; }
        float a = __expf(v1 - v0);
        float inv = 1.f / (1.f + a);
        int2 ei; ei.x = e0; ei.y = e1;
        float2 pp; pp.x = inv; pp.y = a * inv;
        eidx[tok] = ei;
        probs[tok] = pp;
        atomicAdd(&meta[e0], 1);
        atomicAdd(&meta[e1], 1);
    }
}

// ---------------------------------------------------------------- weight convert+transpose
// Wg/Wu -> wcat[e][n'][k-int] with 16-col g/u interleave; Wd -> wdt[e][n][k-int]
__global__ __launch_bounds__(256) void convert_kernel(
    const float* __restrict__ Wg, const float* __restrict__ Wu,
    const float* __restrict__ Wd, unsigned short* __restrict__ wcat,
    unsigned short* __restrict__ wdt) {
    int mz = blockIdx.z;
    int mat = mz >> 3, e = mz & 7;
    const float* W = (mat == 0 ? Wg : (mat == 1 ? Wu : Wd)) + (size_t)e * HID * HID;
    int kb = blockIdx.y * 64, nb = blockIdx.x * 64;
    __shared__ unsigned short t[64][68];
    int tid = threadIdx.x;
    int kr = tid >> 4;
    int nc = (tid & 15) * 4;
#pragma unroll
    for (int ki = 0; ki < 4; ++ki) {
        int k = kr + ki * 16;
        float4 v = *(const float4*)&W[(size_t)(kb + k) * HID + nb + nc];
        t[nc + 0][k] = f2bf(v.x);
        t[nc + 1][k] = f2bf(v.y);
        t[nc + 2][k] = f2bf(v.z);
        t[nc + 3][k] = f2bf(v.w);
    }
    __syncthreads();
    int q = tid & 15;
    int k0 = ((q >> 3) << 5) + (((q >> 1) & 3) << 2) + ((q & 1) << 4);
#pragma unroll
    for (int ni = 0; ni < 4; ++ni) {
        int n = (tid >> 4) + ni * 16;
        int gn = nb + n;
        unsigned short* orow;
        if (mat < 2)
            orow = wcat + ((size_t)e * 4096 + (gn >> 4) * 32 + mat * 16 + (gn & 15)) * HID;
        else
            orow = wdt + ((size_t)e * HID + gn) * HID;
        unsigned long long pk = (unsigned long long)t[n][k0]
                              | ((unsigned long long)t[n][k0 + 1] << 16)
                              | ((unsigned long long)t[n][k0 + 2] << 32)
                              | ((unsigned long long)t[n][k0 + 3] << 48);
        *(unsigned long long*)&orow[kb + q * 4] = pk;
    }
}

// ---------------------------------------------------------------- scan
__global__ void scan_kernel(int* __restrict__ meta) {
    if (threadIdx.x == 0) {
        int s = 0;
#pragma unroll
        for (int e = 0; e < NEXP; ++e) { meta[16 + e] = s; s += meta[e]; }
    }
}

// ---------------------------------------------------------------- build expanded rows
__global__ __launch_bounds__(256) void build_kernel(
    const int2* __restrict__ eidx, const float2* __restrict__ probs,
    int* __restrict__ meta, int* __restrict__ row_token, float* __restrict__ row_prob) {
    int t = blockIdx.x * 256 + threadIdx.x;
    if (t >= TOKENS) return;
    int2 e = eidx[t];
    float2 p = probs[t];
    int s0 = meta[16 + e.x] + atomicAdd(&meta[8 + e.x], 1);
    row_token[s0] = t; row_prob[s0] = p.x;
    int s1 = meta[16 + e.y] + atomicAdd(&meta[8 + e.y], 1);
    row_token[s1] = t; row_prob[s1] = p.y;
}

// ---------------------------------------------------------------- 8-phase GEMM macros
// LDS map: A half (d,kh) at d*32768 + kh*16384 ; B half at +65536. 128 KiB total.
#define STA(dn, kh, tt) { char* _d = lds + (dn)*32768 + (kh)*16384 + tid*16; \
    gload16(_d,        a0 + (tt)*64 + (kh)*32); \
    gload16(_d + 8192, a1 + (tt)*64 + (kh)*32); }
#define STB(dn, kh, tt) { char* _d = lds + (dn)*32768 + 65536 + (kh)*16384 + tid*16; \
    gload16(_d,        b0 + (tt)*64 + (kh)*32); \
    gload16(_d + 8192, b1 + (tt)*64 + (kh)*32); }
#define LDA(d, kh) { const char* _b = lds + (d)*32768 + (kh)*16384 + afo; \
    af[0] = *(const bf16x8*)(_b);          af[1] = *(const bf16x8*)(_b + 1024); \
    af[2] = *(const bf16x8*)(_b + 2048);   af[3] = *(const bf16x8*)(_b + 3072); \
    af[4] = *(const bf16x8*)(_b + 4096);   af[5] = *(const bf16x8*)(_b + 5120); \
    af[6] = *(const bf16x8*)(_b + 6144);   af[7] = *(const bf16x8*)(_b + 7168); }
#define LDB(d, kh, nn) (*(const bf16x8*)(lds + (d)*32768 + (kh)*16384 + bfo + (nn)*1024))
#define MM(n0, n1) do { \
    __builtin_amdgcn_s_setprio(1); \
    _Pragma("unroll") \
    for (int m = 0; m < 8; ++m) { \
        acc[m][n0] = __builtin_amdgcn_mfma_f32_16x16x32_bf16(af[m], bq0, acc[m][n0], 0, 0, 0); \
        acc[m][n1] = __builtin_amdgcn_mfma_f32_16x16x32_bf16(af[m], bq1, acc[m][n1], 0, 0, 0); \
    } \
    __builtin_amdgcn_s_setprio(0); \
} while (0)

#define GEMM_MAIN_LOOP \
    { STA(0, 0, 0); STB(0, 0, 0); STA(0, 1, 0); STB(0, 1, 0); } \
    VM4; BAR; \
    for (int t = 0; t < NT - 1; ++t) { \
        const int d = t & 1, dn = d ^ 1, tn = t + 1; \
        bf16x8 bq0, bq1; \
        LDA(d, 0); bq0 = LDB(d, 0, 0); bq1 = LDB(d, 0, 1); \
        STA(dn, 0, tn); \
        MM(0, 1); \
        BAR; \
        bq0 = LDB(d, 0, 2); bq1 = LDB(d, 0, 3); \
        STB(dn, 0, tn); \
        MM(2, 3); \
        VM4; BAR; \
        LDA(d, 1); bq0 = LDB(d, 1, 0); bq1 = LDB(d, 1, 1); \
        STA(dn, 1, tn); \
        MM(0, 1); \
        BAR; \
        bq0 = LDB(d, 1, 2); bq1 = LDB(d, 1, 3); \
        STB(dn, 1, tn); \
        MM(2, 3); \
        VM4; BAR; \
    } \
    { const int d = (NT - 1) & 1; \
        bf16x8 bq0, bq1; \
        LDA(d, 0); bq0 = LDB(d, 0, 0); bq1 = LDB(d, 0, 1); MM(0, 1); \
        bq0 = LDB(d, 0, 2); bq1 = LDB(d, 0, 3); MM(2, 3); \
        VM0; BAR; \
        LDA(d, 1); bq0 = LDB(d, 1, 0); bq1 = LDB(d, 1, 1); MM(0, 1); \
        bq0 = LDB(d, 1, 2); bq1 = LDB(d, 1, 3); MM(2, 3); \
    }

// ---------------------------------------------------------------- GEMM1: act = swiglu(x @ wcat)
__global__ __launch_bounds__(512) void gemm1_kernel(
    const unsigned short* __restrict__ xbf, const unsigned short* __restrict__ wcat,
    const int* __restrict__ row_token, const int* __restrict__ meta,
    unsigned short* __restrict__ act) {
    int e = blockIdx.z;
    int cnt = meta[e];
    int rt = blockIdx.y;
    if (rt * 256 >= cnt) return;
    int off = meta[16 + e];
    int ct = blockIdx.x;                 // 0..15 over N'=4096
    __shared__ __align__(16) char lds[131072];
    int tid = threadIdx.x, w = tid >> 6, l = tid & 63;
    int wr = w >> 2, wc = w & 3;
    int r16 = l & 15, g = l >> 4;

    // staging sources
    int sg = tid & 3, srow = tid >> 2;
    int rr0 = rt * 256 + srow;       if (rr0 >= cnt) rr0 = cnt - 1;
    int rr1 = rt * 256 + srow + 128; if (rr1 >= cnt) rr1 = cnt - 1;
    const unsigned short* a0 = xbf + (size_t)row_token[off + rr0] * HID + sg * 8;
    const unsigned short* a1 = xbf + (size_t)row_token[off + rr1] * HID + sg * 8;
    const unsigned short* b0 = wcat + ((size_t)(e * 4096 + ct * 256 + srow)) * HID + sg * 8;
    const unsigned short* b1 = b0 + (size_t)128 * HID;

    int afo = (wr * 128 + r16) * 64 + g * 16;
    int bfo = 65536 + (wc * 64 + r16) * 64 + g * 16;

    f32x4 acc[8][4];
    f32x4 z = {0.f, 0.f, 0.f, 0.f};
#pragma unroll
    for (int m = 0; m < 8; ++m)
#pragma unroll
        for (int nn = 0; nn < 4; ++nn) acc[m][nn] = z;
    bf16x8 af[8];

    GEMM_MAIN_LOOP

    // epilogue: swiglu on (g,u) frag pairs, store act interleaved-k
    int pb = (ct * 4 + wc) * 32 + (r16 >> 2) * 8 + (r16 & 3);  // + p*4
#pragma unroll
    for (int m = 0; m < 8; ++m) {
        int rbase = wr * 128 + m * 16 + (l >> 4) * 4;
#pragma unroll
        for (int q = 0; q < 4; ++q) {
            int r = rt * 256 + rbase + q;
            if (r < cnt) {
                unsigned short* arow = act + (size_t)(off + r) * HID;
#pragma unroll
                for (int p = 0; p < 2; ++p) {
                    float gg = acc[m][2 * p][q];
                    float uu = acc[m][2 * p + 1][q];
                    float s = gg / (1.f + __expf(-gg));
                    s = fminf(fmaxf(s, -7.f), 7.f);
                    arow[pb + p * 4] = f2bf(s * uu);
                }
            }
        }
    }
}

// ---------------------------------------------------------------- GEMM2: out += p * (act @ wdt)
__global__ __launch_bounds__(512) void gemm2_kernel(
    const unsigned short* __restrict__ act, const unsigned short* __restrict__ wdt,
    const int* __restrict__ row_token, const float* __restrict__ row_prob,
    const int* __restrict__ meta, float* __restrict__ out) {
    int e = blockIdx.z;
    int cnt = meta[e];
    int rt = blockIdx.y;
    if (rt * 256 >= cnt) return;
    int off = meta[16 + e];
    int ct = blockIdx.x;                 // 0..7 over N=2048
    __shared__ __align__(16) char lds[131072];
    int tid = threadIdx.x, w = tid >> 6, l = tid & 63;
    int wr = w >> 2, wc = w & 3;
    int r16 = l & 15, g = l >> 4;

    int sg = tid & 3, srow = tid >> 2;
    int rr0 = rt * 256 + srow;       if (rr0 >= cnt) rr0 = cnt - 1;
    int rr1 = rt * 256 + srow + 128; if (rr1 >= cnt) rr1 = cnt - 1;
    const unsigned short* a0 = act + (size_t)(off + rr0) * HID + sg * 8;
    const unsigned short* a1 = act + (size_t)(off + rr1) * HID + sg * 8;
    const unsigned short* b0 = wdt + ((size_t)(e * HID + ct * 256 + srow)) * HID + sg * 8;
    const unsigned short* b1 = b0 + (size_t)128 * HID;

    int afo = (wr * 128 + r16) * 64 + g * 16;
    int bfo = 65536 + (wc * 64 + r16) * 64 + g * 16;

    f32x4 acc[8][4];
    f32x4 z = {0.f, 0.f, 0.f, 0.f};
#pragma unroll
    for (int m = 0; m < 8; ++m)
#pragma unroll
        for (int nn = 0; nn < 4; ++nn) acc[m][nn] = z;
    bf16x8 af[8];

    GEMM_MAIN_LOOP

    int colb = ct * 256 + wc * 64;
#pragma unroll
    for (int m = 0; m < 8; ++m) {
        int rbase = wr * 128 + m * 16 + (l >> 4) * 4;
#pragma unroll
        for (int q = 0; q < 4; ++q) {
            int r = rt * 256 + rbase + q;
            if (r < cnt) {
                int slot = off + r;
                int tok = row_token[slot];
                float pr = row_prob[slot];
                float* orow = out + (size_t)tok * HID + colb;
#pragma unroll
                for (int nn = 0; nn < 4; ++nn)
                    unsafeAtomicAdd(&orow[nn * 16 + r16], acc[m][nn][q] * pr);
            }
        }
    }
}

// ---------------------------------------------------------------- launch
extern "C" void kernel_launch(void* const* d_in, const int* in_sizes, int n_in,
                              void* d_out, int out_size, void* d_ws, size_t ws_size,
                              hipStream_t stream) {
    const float* x  = (const float*)d_in[0];
    const float* Wr = (const float*)d_in[1];
    const float* Wg = (const float*)d_in[2];
    const float* Wu = (const float*)d_in[3];
    const float* Wd = (const float*)d_in[4];
    float* out = (float*)d_out;
    char* ws = (char*)d_ws;

    unsigned short* xbf  = (unsigned short*)(ws + WS_XBF);
    unsigned short* act  = (unsigned short*)(ws + WS_ACT);
    unsigned short* wcat = (unsigned short*)(ws + WS_WCAT);
    unsigned short* wdt  = (unsigned short*)(ws + WS_WDT);
    int* row_token  = (int*)(ws + WS_ROWTOK);
    float* row_prob = (float*)(ws + WS_ROWPROB);
    int2* eidx      = (int2*)(ws + WS_EIDX);
    float2* probs   = (float2*)(ws + WS_PROBS);
    int* meta       = (int*)(ws + WS_META);

    hipMemsetAsync(d_out, 0, (size_t)out_size * sizeof(float), stream);
    hipMemsetAsync(meta, 0, 64, stream);

    hipLaunchKernelGGL(convert_kernel, dim3(32, 32, 24), dim3(256), 0, stream,
                       Wg, Wu, Wd, wcat, wdt);
    hipLaunchKernelGGL(router_kernel, dim3(TOKENS / 4), dim3(256), 0, stream,
                       x, Wr, xbf, eidx, probs, meta);
    hipLaunchKernelGGL(scan_kernel, dim3(1), dim3(64), 0, stream, meta);
    hipLaunchKernelGGL(build_kernel, dim3(TOKENS / 256), dim3(256), 0, stream,
                       eidx, probs, meta, row_token, row_prob);
    hipLaunchKernelGGL(gemm1_kernel, dim3(16, 64, NEXP), dim3(512), 0, stream,
                       xbf, wcat, row_token, meta, act);
    hipLaunchKernelGGL(gemm2_kernel, dim3(8, 64, NEXP), dim3(512), 0, stream,
                       act, wdt, row_token, row_prob, meta, out);
}

// Round 4
// 908.654 us; speedup vs baseline: 1.4620x; 1.0333x over previous
//
#include <hip/hip_runtime.h>

#define TOKENS 8192
#define HID 2048
#define NEXP 8
#define NT 32          // K tiles = 2048/64

typedef float f32x4 __attribute__((ext_vector_type(4)));
typedef short bf16x8 __attribute__((ext_vector_type(8)));

// ws layout (bytes)
#define WS_XBF     0ULL           // 8192 x 2048 bf16 (interleaved k)
#define WS_ACT     33554432ULL    // 16384 x 2048 bf16 (interleaved k)
#define WS_WCAT    100663296ULL   // 8 x 4096 x 2048 bf16  [e][n'][k-int], n' = g/u 16-col interleave
#define WS_WDT     234881024ULL   // 8 x 2048 x 2048 bf16  [e][n][k-int]
#define WS_ROWTOK  301989888ULL   // 16384 int
#define WS_ROWPROB 302055424ULL   // 16384 float
#define WS_EIDX    302120960ULL   // 8192 int2
#define WS_PROBS   302186496ULL   // 8192 float2
#define WS_META    302252032ULL   // [0..7]=counts [8..15]=fill [16..23]=offsets

__device__ __forceinline__ unsigned short f2bf(float f) {
    union { float f; unsigned int u; } a; a.f = f;
    unsigned int r = a.u + 0x7fffu + ((a.u >> 16) & 1u);
    return (unsigned short)(r >> 16);
}

__device__ __forceinline__ void gload16(void* ldsdst, const void* gsrc) {
    __builtin_amdgcn_global_load_lds(
        (const __attribute__((address_space(1))) void*)gsrc,
        (__attribute__((address_space(3))) void*)ldsdst, 16, 0, 0);
}

#define BAR asm volatile("s_barrier" ::: "memory")
#define VM4 asm volatile("s_waitcnt vmcnt(4)" ::: "memory")
#define VM0 asm volatile("s_waitcnt vmcnt(0)" ::: "memory")

// ---------------------------------------------------------------- router
__global__ __launch_bounds__(256) void router_kernel(
    const float* __restrict__ x, const float* __restrict__ Wr,
    unsigned short* __restrict__ xbf, int2* __restrict__ eidx,
    float2* __restrict__ probs, int* __restrict__ meta) {
    __shared__ float wrt[NEXP * HID];   // 64 KiB, [e][i]
    int tid = threadIdx.x;
    for (int f = tid; f < HID * NEXP; f += 256) {
        int i = f >> 3, e = f & 7;
        wrt[e * HID + i] = Wr[f];
    }
    __syncthreads();
    int w = tid >> 6, l = tid & 63;
    int tok = blockIdx.x * 4 + w;
    const float4* xr = (const float4*)(x + (size_t)tok * HID);
    float acc[NEXP];
#pragma unroll
    for (int e = 0; e < NEXP; ++e) acc[e] = 0.f;
    unsigned long long* xbr = (unsigned long long*)(xbf + (size_t)tok * HID);
#pragma unroll
    for (int it = 0; it < 8; ++it) {
        float4 v = xr[it * 64 + l];
        int k0 = (it * 64 + l) * 4;
#pragma unroll
        for (int e = 0; e < NEXP; ++e) {
            float4 wv = *(const float4*)&wrt[e * HID + k0];
            acc[e] += v.x * wv.x + v.y * wv.y + v.z * wv.z + v.w * wv.w;
        }
        unsigned long long pk = (unsigned long long)f2bf(v.x)
                              | ((unsigned long long)f2bf(v.y) << 16)
                              | ((unsigned long long)f2bf(v.z) << 32)
                              | ((unsigned long long)f2bf(v.w) << 48);
        int qi = ((k0 >> 5) << 3) + (((k0 >> 2) & 3) << 1) + ((k0 >> 4) & 1);
        xbr[qi] = pk;
    }
#pragma unroll
    for (int e = 0; e < NEXP; ++e) {
#pragma unroll
        for (int d = 1; d < 64; d <<= 1) acc[e] += __shfl_xor(acc[e], d, 64);
    }
    if (l == 0) {
        int e0 = 0; float v0 = acc[0];
#pragma unroll
        for (int e = 1; e < NEXP; ++e) if (acc[e] > v0) { v0 = acc[e]; e0 = e; }
        int e1 = -1; float v1 = 0.f;
#pragma unroll
        for (int e = 0; e < NEXP; ++e)
            if (e != e0 && (e1 < 0 || acc[e] > v1)) { v1 = acc[e]; e1 = e; }
        float a = __expf(v1 - v0);
        float inv = 1.f / (1.f + a);
        int2 ei; ei.x = e0; ei.y = e1;
        float2 pp; pp.x = inv; pp.y = a * inv;
        eidx[tok] = ei;
        probs[tok] = pp;
        atomicAdd(&meta[e0], 1);
        atomicAdd(&meta[e1], 1);
    }
}

// ---------------------------------------------------------------- weight convert+transpose
// Wg/Wu -> wcat[e][n'][k-int] with 16-col g/u interleave; Wd -> wdt[e][n][k-int]
__global__ __launch_bounds__(256) void convert_kernel(
    const float* __restrict__ Wg, const float* __restrict__ Wu,
    const float* __restrict__ Wd, unsigned short* __restrict__ wcat,
    unsigned short* __restrict__ wdt) {
    int mz = blockIdx.z;
    int mat = mz >> 3, e = mz & 7;
    const float* W = (mat == 0 ? Wg : (mat == 1 ? Wu : Wd)) + (size_t)e * HID * HID;
    int kb = blockIdx.y * 64, nb = blockIdx.x * 64;
    __shared__ unsigned short t[64][68];
    int tid = threadIdx.x;
    int kr = tid >> 4;
    int nc = (tid & 15) * 4;
#pragma unroll
    for (int ki = 0; ki < 4; ++ki) {
        int k = kr + ki * 16;
        float4 v = *(const float4*)&W[(size_t)(kb + k) * HID + nb + nc];
        t[nc + 0][k] = f2bf(v.x);
        t[nc + 1][k] = f2bf(v.y);
        t[nc + 2][k] = f2bf(v.z);
        t[nc + 3][k] = f2bf(v.w);
    }
    __syncthreads();
    int q = tid & 15;
    int k0 = ((q >> 3) << 5) + (((q >> 1) & 3) << 2) + ((q & 1) << 4);
#pragma unroll
    for (int ni = 0; ni < 4; ++ni) {
        int n = (tid >> 4) + ni * 16;
        int gn = nb + n;
        unsigned short* orow;
        if (mat < 2)
            orow = wcat + ((size_t)e * 4096 + (gn >> 4) * 32 + mat * 16 + (gn & 15)) * HID;
        else
            orow = wdt + ((size_t)e * HID + gn) * HID;
        unsigned long long pk = (unsigned long long)t[n][k0]
                              | ((unsigned long long)t[n][k0 + 1] << 16)
                              | ((unsigned long long)t[n][k0 + 2] << 32)
                              | ((unsigned long long)t[n][k0 + 3] << 48);
        *(unsigned long long*)&orow[kb + q * 4] = pk;
    }
}

// ---------------------------------------------------------------- scan
__global__ void scan_kernel(int* __restrict__ meta) {
    if (threadIdx.x == 0) {
        int s = 0;
#pragma unroll
        for (int e = 0; e < NEXP; ++e) { meta[16 + e] = s; s += meta[e]; }
    }
}

// ---------------------------------------------------------------- build expanded rows
__global__ __launch_bounds__(256) void build_kernel(
    const int2* __restrict__ eidx, const float2* __restrict__ probs,
    int* __restrict__ meta, int* __restrict__ row_token, float* __restrict__ row_prob) {
    int t = blockIdx.x * 256 + threadIdx.x;
    if (t >= TOKENS) return;
    int2 e = eidx[t];
    float2 p = probs[t];
    int s0 = meta[16 + e.x] + atomicAdd(&meta[8 + e.x], 1);
    row_token[s0] = t; row_prob[s0] = p.x;
    int s1 = meta[16 + e.y] + atomicAdd(&meta[8 + e.y], 1);
    row_token[s1] = t; row_prob[s1] = p.y;
}

// ---------------------------------------------------------------- 8-phase GEMM macros
// LDS map: A half (d,kh) at d*32768 + kh*16384 ; B half at +65536. 128 KiB total.
// Bank swizzle: physical 16B unit u of LDS row r holds logical unit u ^ ((r>>1)&3).
// Write side: gload_lds dest linear, per-lane GLOBAL source pre-swizzled (sxu).
// Read side: fragment unit = g ^ ((r16>>1)&3). Within each 16-lane read phase
// lanes spread 2-per-bank-quad (free) instead of 8-way.
#define STA(dn, kh, tt) { char* _d = lds + (dn)*32768 + (kh)*16384 + tid*16; \
    gload16(_d,        a0 + (tt)*64 + (kh)*32); \
    gload16(_d + 8192, a1 + (tt)*64 + (kh)*32); }
#define STB(dn, kh, tt) { char* _d = lds + (dn)*32768 + 65536 + (kh)*16384 + tid*16; \
    gload16(_d,        b0 + (tt)*64 + (kh)*32); \
    gload16(_d + 8192, b1 + (tt)*64 + (kh)*32); }
#define LDA(d, kh) { const char* _b = lds + (d)*32768 + (kh)*16384 + afo; \
    af[0] = *(const bf16x8*)(_b);          af[1] = *(const bf16x8*)(_b + 1024); \
    af[2] = *(const bf16x8*)(_b + 2048);   af[3] = *(const bf16x8*)(_b + 3072); \
    af[4] = *(const bf16x8*)(_b + 4096);   af[5] = *(const bf16x8*)(_b + 5120); \
    af[6] = *(const bf16x8*)(_b + 6144);   af[7] = *(const bf16x8*)(_b + 7168); }
#define LDB(d, kh, nn) (*(const bf16x8*)(lds + (d)*32768 + (kh)*16384 + bfo + (nn)*1024))
#define MM(n0, n1) do { \
    __builtin_amdgcn_s_setprio(1); \
    _Pragma("unroll") \
    for (int m = 0; m < 8; ++m) { \
        acc[m][n0] = __builtin_amdgcn_mfma_f32_16x16x32_bf16(af[m], bq0, acc[m][n0], 0, 0, 0); \
        acc[m][n1] = __builtin_amdgcn_mfma_f32_16x16x32_bf16(af[m], bq1, acc[m][n1], 0, 0, 0); \
    } \
    __builtin_amdgcn_s_setprio(0); \
} while (0)

#define GEMM_MAIN_LOOP \
    { STA(0, 0, 0); STB(0, 0, 0); STA(0, 1, 0); STB(0, 1, 0); } \
    VM4; BAR; \
    for (int t = 0; t < NT - 1; ++t) { \
        const int d = t & 1, dn = d ^ 1, tn = t + 1; \
        bf16x8 bq0, bq1; \
        LDA(d, 0); bq0 = LDB(d, 0, 0); bq1 = LDB(d, 0, 1); \
        STA(dn, 0, tn); \
        MM(0, 1); \
        BAR; \
        bq0 = LDB(d, 0, 2); bq1 = LDB(d, 0, 3); \
        STB(dn, 0, tn); \
        MM(2, 3); \
        VM4; BAR; \
        LDA(d, 1); bq0 = LDB(d, 1, 0); bq1 = LDB(d, 1, 1); \
        STA(dn, 1, tn); \
        MM(0, 1); \
        BAR; \
        bq0 = LDB(d, 1, 2); bq1 = LDB(d, 1, 3); \
        STB(dn, 1, tn); \
        MM(2, 3); \
        VM4; BAR; \
    } \
    { const int d = (NT - 1) & 1; \
        bf16x8 bq0, bq1; \
        LDA(d, 0); bq0 = LDB(d, 0, 0); bq1 = LDB(d, 0, 1); MM(0, 1); \
        bq0 = LDB(d, 0, 2); bq1 = LDB(d, 0, 3); MM(2, 3); \
        VM0; BAR; \
        LDA(d, 1); bq0 = LDB(d, 1, 0); bq1 = LDB(d, 1, 1); MM(0, 1); \
        bq0 = LDB(d, 1, 2); bq1 = LDB(d, 1, 3); MM(2, 3); \
    }

// ---------------------------------------------------------------- GEMM1: act = swiglu(x @ wcat)
__global__ __launch_bounds__(512) void gemm1_kernel(
    const unsigned short* __restrict__ xbf, const unsigned short* __restrict__ wcat,
    const int* __restrict__ row_token, const int* __restrict__ meta,
    unsigned short* __restrict__ act) {
    int e = blockIdx.z;
    int cnt = meta[e];
    int rt = blockIdx.y;
    if (rt * 256 >= cnt) return;
    int off = meta[16 + e];
    int ct = blockIdx.x;                 // 0..15 over N'=4096
    __shared__ __align__(16) char lds[131072];
    int tid = threadIdx.x, w = tid >> 6, l = tid & 63;
    int wr = w >> 2, wc = w & 3;
    int r16 = l & 15, g = l >> 4;

    // staging sources (pre-swizzled unit within row)
    int srow = tid >> 2;
    int sxu = (tid & 3) ^ ((tid >> 3) & 3);
    int rr0 = rt * 256 + srow;       if (rr0 >= cnt) rr0 = cnt - 1;
    int rr1 = rt * 256 + srow + 128; if (rr1 >= cnt) rr1 = cnt - 1;
    const unsigned short* a0 = xbf + (size_t)row_token[off + rr0] * HID + sxu * 8;
    const unsigned short* a1 = xbf + (size_t)row_token[off + rr1] * HID + sxu * 8;
    const unsigned short* b0 = wcat + ((size_t)(e * 4096 + ct * 256 + srow)) * HID + sxu * 8;
    const unsigned short* b1 = b0 + (size_t)128 * HID;

    int sw = (r16 >> 1) & 3;
    int afo = (wr * 128 + r16) * 64 + (g ^ sw) * 16;
    int bfo = 65536 + (wc * 64 + r16) * 64 + (g ^ sw) * 16;

    f32x4 acc[8][4];
    f32x4 z = {0.f, 0.f, 0.f, 0.f};
#pragma unroll
    for (int m = 0; m < 8; ++m)
#pragma unroll
        for (int nn = 0; nn < 4; ++nn) acc[m][nn] = z;
    bf16x8 af[8];

    GEMM_MAIN_LOOP

    // epilogue: swiglu on (g,u) frag pairs, store act interleaved-k
    int pb = (ct * 4 + wc) * 32 + (r16 >> 2) * 8 + (r16 & 3);  // + p*4
#pragma unroll
    for (int m = 0; m < 8; ++m) {
        int rbase = wr * 128 + m * 16 + (l >> 4) * 4;
#pragma unroll
        for (int q = 0; q < 4; ++q) {
            int r = rt * 256 + rbase + q;
            if (r < cnt) {
                unsigned short* arow = act + (size_t)(off + r) * HID;
#pragma unroll
                for (int p = 0; p < 2; ++p) {
                    float gg = acc[m][2 * p][q];
                    float uu = acc[m][2 * p + 1][q];
                    float s = gg / (1.f + __expf(-gg));
                    s = fminf(fmaxf(s, -7.f), 7.f);
                    arow[pb + p * 4] = f2bf(s * uu);
                }
            }
        }
    }
}

// ---------------------------------------------------------------- GEMM2: out += p * (act @ wdt)
__global__ __launch_bounds__(512) void gemm2_kernel(
    const unsigned short* __restrict__ act, const unsigned short* __restrict__ wdt,
    const int* __restrict__ row_token, const float* __restrict__ row_prob,
    const int* __restrict__ meta, float* __restrict__ out) {
    int e = blockIdx.z;
    int cnt = meta[e];
    int rt = blockIdx.y;
    if (rt * 256 >= cnt) return;
    int off = meta[16 + e];
    int ct = blockIdx.x;                 // 0..7 over N=2048
    __shared__ __align__(16) char lds[131072];
    int tid = threadIdx.x, w = tid >> 6, l = tid & 63;
    int wr = w >> 2, wc = w & 3;
    int r16 = l & 15, g = l >> 4;

    int srow = tid >> 2;
    int sxu = (tid & 3) ^ ((tid >> 3) & 3);
    int rr0 = rt * 256 + srow;       if (rr0 >= cnt) rr0 = cnt - 1;
    int rr1 = rt * 256 + srow + 128; if (rr1 >= cnt) rr1 = cnt - 1;
    const unsigned short* a0 = act + (size_t)(off + rr0) * HID + sxu * 8;
    const unsigned short* a1 = act + (size_t)(off + rr1) * HID + sxu * 8;
    const unsigned short* b0 = wdt + ((size_t)(e * HID + ct * 256 + srow)) * HID + sxu * 8;
    const unsigned short* b1 = b0 + (size_t)128 * HID;

    int sw = (r16 >> 1) & 3;
    int afo = (wr * 128 + r16) * 64 + (g ^ sw) * 16;
    int bfo = 65536 + (wc * 64 + r16) * 64 + (g ^ sw) * 16;

    f32x4 acc[8][4];
    f32x4 z = {0.f, 0.f, 0.f, 0.f};
#pragma unroll
    for (int m = 0; m < 8; ++m)
#pragma unroll
        for (int nn = 0; nn < 4; ++nn) acc[m][nn] = z;
    bf16x8 af[8];

    GEMM_MAIN_LOOP

    int colb = ct * 256 + wc * 64;
#pragma unroll
    for (int m = 0; m < 8; ++m) {
        int rbase = wr * 128 + m * 16 + (l >> 4) * 4;
#pragma unroll
        for (int q = 0; q < 4; ++q) {
            int r = rt * 256 + rbase + q;
            if (r < cnt) {
                int slot = off + r;
                int tok = row_token[slot];
                float pr = row_prob[slot];
                float* orow = out + (size_t)tok * HID + colb;
#pragma unroll
                for (int nn = 0; nn < 4; ++nn)
                    unsafeAtomicAdd(&orow[nn * 16 + r16], acc[m][nn][q] * pr);
            }
        }
    }
}

// ---------------------------------------------------------------- launch
extern "C" void kernel_launch(void* const* d_in, const int* in_sizes, int n_in,
                              void* d_out, int out_size, void* d_ws, size_t ws_size,
                              hipStream_t stream) {
    const float* x  = (const float*)d_in[0];
    const float* Wr = (const float*)d_in[1];
    const float* Wg = (const float*)d_in[2];
    const float* Wu = (const float*)d_in[3];
    const float* Wd = (const float*)d_in[4];
    float* out = (float*)d_out;
    char* ws = (char*)d_ws;

    unsigned short* xbf  = (unsigned short*)(ws + WS_XBF);
    unsigned short* act  = (unsigned short*)(ws + WS_ACT);
    unsigned short* wcat = (unsigned short*)(ws + WS_WCAT);
    unsigned short* wdt  = (unsigned short*)(ws + WS_WDT);
    int* row_token  = (int*)(ws + WS_ROWTOK);
    float* row_prob = (float*)(ws + WS_ROWPROB);
    int2* eidx      = (int2*)(ws + WS_EIDX);
    float2* probs   = (float2*)(ws + WS_PROBS);
    int* meta       = (int*)(ws + WS_META);

    hipMemsetAsync(d_out, 0, (size_t)out_size * sizeof(float), stream);
    hipMemsetAsync(meta, 0, 64, stream);

    hipLaunchKernelGGL(convert_kernel, dim3(32, 32, 24), dim3(256), 0, stream,
                       Wg, Wu, Wd, wcat, wdt);
    hipLaunchKernelGGL(router_kernel, dim3(TOKENS / 4), dim3(256), 0, stream,
                       x, Wr, xbf, eidx, probs, meta);
    hipLaunchKernelGGL(scan_kernel, dim3(1), dim3(64), 0, stream, meta);
    hipLaunchKernelGGL(build_kernel, dim3(TOKENS / 256), dim3(256), 0, stream,
                       eidx, probs, meta, row_token, row_prob);
    hipLaunchKernelGGL(gemm1_kernel, dim3(16, 64, NEXP), dim3(512), 0, stream,
                       xbf, wcat, row_token, meta, act);
    hipLaunchKernelGGL(gemm2_kernel, dim3(8, 64, NEXP), dim3(512), 0, stream,
                       act, wdt, row_token, row_prob, meta, out);
}